// Round 3
// baseline (245.433 us; speedup 1.0000x reference)
//
#include <hip/hip_runtime.h>

#define DIM 2048

typedef float fvec4 __attribute__((ext_vector_type(4)));

// XOR-swizzle LDS float-index: bits 2..4 ^= bits 7..9. Keeps 16B (4-float)
// alignment (bits 0-1 untouched); makes all four transpose phases hit each
// bank-group exactly 8x per b128 op (minimum).
__device__ __forceinline__ int sw(int e) {
  return e ^ (((e >> 7) & 7) << 2);
}

// Compiler-only memory fence: per-wave LDS slices + in-order DS pipe mean no
// s_barrier is needed; we only must stop the COMPILER from reordering the
// cross-lane LDS read/write phases. Emits no hardware instructions.
__device__ __forceinline__ void wv_fence() {
  asm volatile("" ::: "memory");
  __builtin_amdgcn_wave_barrier();
}

// Flip sign of x iff bit b of mask m is set (b is compile-time constant).
__device__ __forceinline__ float flipbit(float x, unsigned m, int b) {
  return __uint_as_float(__float_as_uint(x) ^ ((m << (31 - b)) & 0x80000000u));
}

#define BFLY(a, b) { float _t = (a); (a) = _t + (b); (b) = _t - (b); }

__device__ __forceinline__ void bf4_pair(float4 &a, float4 &b) {
  BFLY(a.x, b.x); BFLY(a.y, b.y); BFLY(a.z, b.z); BFLY(a.w, b.w);
}

// Butterfly element-index bits 0 and 1 (within the float4 components).
__device__ __forceinline__ void bf_comps(float4 &a) {
  BFLY(a.x, a.y); BFLY(a.z, a.w);   // bit 0
  BFLY(a.x, a.z); BFLY(a.y, a.w);   // bit 1
}

// Butterfly the 3 bits of the 8-register index (strides 1,2,4).
__device__ __forceinline__ void bf_oct(float4 v[8]) {
  bf4_pair(v[0], v[1]); bf4_pair(v[2], v[3]);
  bf4_pair(v[4], v[5]); bf4_pair(v[6], v[7]);
  bf4_pair(v[0], v[2]); bf4_pair(v[1], v[3]);
  bf4_pair(v[4], v[6]); bf4_pair(v[5], v[7]);
  bf4_pair(v[0], v[4]); bf4_pair(v[1], v[5]);
  bf4_pair(v[2], v[6]); bf4_pair(v[3], v[7]);
}

// Cross-lane butterfly on lane bit 0 / 1 via DPP quad_perm (VALU rate).
// 0xB1 = [1,0,3,2] (xor1), 0x4E = [2,3,0,1] (xor2).
template <int CTRL>
__device__ __forceinline__ float dpp_mov(float x) {
  return __int_as_float(
      __builtin_amdgcn_mov_dpp(__float_as_int(x), CTRL, 0xF, 0xF, true));
}

template <int CTRL>
__device__ __forceinline__ void dpp_stage(float4 v[8], float sgn) {
  #pragma unroll
  for (int i = 0; i < 8; ++i) {
    float px = dpp_mov<CTRL>(v[i].x);
    float py = dpp_mov<CTRL>(v[i].y);
    float pz = dpp_mov<CTRL>(v[i].z);
    float pw = dpp_mov<CTRL>(v[i].w);
    v[i].x = fmaf(sgn, v[i].x, px);
    v[i].y = fmaf(sgn, v[i].y, py);
    v[i].z = fmaf(sgn, v[i].z, pz);
    v[i].w = fmaf(sgn, v[i].w, pw);
  }
}

// One wave per row, 4 rows per wave (strided), 32 floats/lane in registers.
// Layout1 (load):          e = c*256 + lane*4 + r
// Layout2 (after xpose 1): e = r + 4*l1 + 8*l2 + 16*j + 128*l0 + 256*(lane>>3)
// Layout3 (after xpose 2): e = r + 4*l1 + 8*l0 + 16*l2 + 32*l3 + 64*l4 + 128*l5 + 256*c
__global__ __launch_bounds__(256) void srht2_kernel(
    const float* __restrict__ x, const int* __restrict__ signs,
    float* __restrict__ out, int rows_per_wave, int total_waves) {
  __shared__ __align__(16) float lds[4][DIM];
  const int lane = threadIdx.x & 63;
  const int wv   = threadIdx.x >> 6;
  const int gw   = blockIdx.x * 4 + wv;        // global wave id

  const float sgn1 = (lane & 1) ? -1.0f : 1.0f;
  const float sgn2 = (lane & 2) ? -1.0f : 1.0f;
  float* L = lds[wv];

  const int rbase = (((lane >> 1) & 1) << 2) | (((lane >> 2) & 1) << 3)
                  | ((lane & 1) << 7) | ((lane >> 3) << 8);
  const int rb2   = ((lane & 1) << 3) | (((lane >> 1) & 1) << 2)
                  | (((lane >> 2) & 1) << 4) | (((lane >> 3) & 1) << 5)
                  | (((lane >> 4) & 1) << 6) | (((lane >> 5) & 1) << 7);

  // ---- pack this lane's sign bits: 32 bits per pass ----
  // mask0 bit (4c+r) = sign of signs[0][c*256 + lane*4 + r]   (layout1)
  // mask1 bit (4j+r) = sign of signs[1][rbase + 16j + r]      (layout2)
  const uint4* __restrict__ s0 = (const uint4*)signs;
  const uint4* __restrict__ s1 = (const uint4*)(signs + DIM);
  unsigned mask0 = 0u, mask1 = 0u;
  #pragma unroll
  for (int c = 0; c < 8; ++c) {
    uint4 u = s0[c * 64 + lane];
    mask0 |= ((u.x >> 31) << (4 * c)) | ((u.y >> 31) << (4 * c + 1))
           | ((u.z >> 31) << (4 * c + 2)) | ((u.w >> 31) << (4 * c + 3));
    uint4 t = s1[(rbase >> 2) + (c << 2)];
    mask1 |= ((t.x >> 31) << (4 * c)) | ((t.y >> 31) << (4 * c + 1))
           | ((t.z >> 31) << (4 * c + 2)) | ((t.w >> 31) << (4 * c + 3));
  }

  const float sc = 1.0f / 2048.0f;

  // Prime the pipeline: load row 0.
  float4 cur[8];
  {
    const float4* xr = (const float4*)(x + (size_t)gw * DIM);
    #pragma unroll
    for (int c = 0; c < 8; ++c) cur[c] = xr[c * 64 + lane];
  }

  #pragma unroll 1
  for (int i = 0; i < rows_per_wave; ++i) {
    const int row = gw + i * total_waves;

    // Prefetch next row; stays in flight across both transposes since no
    // s_barrier / vmcnt(0) drain exists in this loop.
    float4 nxt[8];
    if (i + 1 < rows_per_wave) {
      const float4* xr = (const float4*)(x + (size_t)(row + total_waves) * DIM);
      #pragma unroll
      for (int c = 0; c < 8; ++c) nxt[c] = xr[c * 64 + lane];
    }

    // ---- pass 1 sign flip (bitmask) ----
    #pragma unroll
    for (int c = 0; c < 8; ++c) {
      cur[c].x = flipbit(cur[c].x, mask0, 4 * c + 0);
      cur[c].y = flipbit(cur[c].y, mask0, 4 * c + 1);
      cur[c].z = flipbit(cur[c].z, mask0, 4 * c + 2);
      cur[c].w = flipbit(cur[c].w, mask0, 4 * c + 3);
    }

    // ---- pass 1, pre-transpose: bits 0,1 (comps), 8,9,10 (c), 2,3 (DPP) ----
    #pragma unroll
    for (int c = 0; c < 8; ++c) bf_comps(cur[c]);
    bf_oct(cur);
    dpp_stage<0xB1>(cur, sgn1);   // bit 2
    dpp_stage<0x4E>(cur, sgn2);   // bit 3

    // ---- transpose 1 (private slice, compiler fence only) ----
    wv_fence();
    #pragma unroll
    for (int c = 0; c < 8; ++c)
      *(float4*)(L + sw(c * 256 + lane * 4)) = cur[c];
    wv_fence();
    float4 w[8];
    #pragma unroll
    for (int j = 0; j < 8; ++j)
      w[j] = *(const float4*)(L + sw(rbase + (j << 4)));
    wv_fence();

    // ---- pass 1, post-transpose: bits 4,5,6 (j), 7 (DPP) ----
    bf_oct(w);
    dpp_stage<0xB1>(w, sgn1);     // bit 7 (lane bit 0 in layout2)

    // ---- pass 2 sign flip (bitmask, layout2) ----
    #pragma unroll
    for (int j = 0; j < 8; ++j) {
      w[j].x = flipbit(w[j].x, mask1, 4 * j + 0);
      w[j].y = flipbit(w[j].y, mask1, 4 * j + 1);
      w[j].z = flipbit(w[j].z, mask1, 4 * j + 2);
      w[j].w = flipbit(w[j].w, mask1, 4 * j + 3);
    }

    // ---- pass 2, pre-transpose: bits 0,1 (comps), 4,5,6 (j), 7,2 (DPP) ----
    #pragma unroll
    for (int j = 0; j < 8; ++j) bf_comps(w[j]);
    bf_oct(w);
    dpp_stage<0xB1>(w, sgn1);     // bit 7
    dpp_stage<0x4E>(w, sgn2);     // bit 2

    // ---- transpose 2 ----
    wv_fence();
    #pragma unroll
    for (int j = 0; j < 8; ++j)
      *(float4*)(L + sw(rbase + (j << 4))) = w[j];
    wv_fence();
    float4 v[8];
    #pragma unroll
    for (int c = 0; c < 8; ++c)
      v[c] = *(const float4*)(L + sw(rb2 + (c << 8)));
    wv_fence();

    // ---- pass 2, post-transpose: bits 8,9,10 (c), 3 (DPP) ----
    bf_oct(v);
    dpp_stage<0xB1>(v, sgn1);     // bit 3 (lane bit 0 in layout3)

    // ---- scale (exact pow2) and nontemporal coalesced store ----
    fvec4* orow = (fvec4*)(out + (size_t)row * DIM);
    #pragma unroll
    for (int c = 0; c < 8; ++c) {
      fvec4 t;
      t.x = v[c].x * sc; t.y = v[c].y * sc;
      t.z = v[c].z * sc; t.w = v[c].w * sc;
      __builtin_nontemporal_store(t, &orow[(rb2 >> 2) + (c << 6)]);
    }

    if (i + 1 < rows_per_wave) {
      #pragma unroll
      for (int c = 0; c < 8; ++c) cur[c] = nxt[c];
    }
  }
}

extern "C" void kernel_launch(void* const* d_in, const int* in_sizes, int n_in,
                              void* d_out, int out_size, void* d_ws, size_t ws_size,
                              hipStream_t stream) {
  const float* x     = (const float*)d_in[0];
  const int*   signs = (const int*)d_in[1];
  float*       out   = (float*)d_out;
  const int nrows       = in_sizes[0] / DIM;      // 16384
  const int nblocks     = 1024;                   // 4 waves each
  const int total_waves = nblocks * 4;            // 4096
  const int rows_per_wave = nrows / total_waves;  // 4
  hipLaunchKernelGGL(srht2_kernel, dim3(nblocks), dim3(256), 0, stream,
                     x, signs, out, rows_per_wave, total_waves);
}

// Round 4
// 240.807 us; speedup vs baseline: 1.0192x; 1.0192x over previous
//
#include <hip/hip_runtime.h>

#define DIM 2048

typedef float fvec4 __attribute__((ext_vector_type(4)));
typedef unsigned short ushort_t;

// Flip sign of x iff bit b of mask m is set (b compile-time constant).
__device__ __forceinline__ float flipbit(float x, unsigned m, int b) {
  return __uint_as_float(__float_as_uint(x) ^ ((m << (31 - b)) & 0x80000000u));
}

#define BFLY(a, b) { float _t = (a); (a) = _t + (b); (b) = _t - (b); }

__device__ __forceinline__ void bf4_pair(float4 &a, float4 &b) {
  BFLY(a.x, b.x); BFLY(a.y, b.y); BFLY(a.z, b.z); BFLY(a.w, b.w);
}
// comps: bit0 pairs (x,y),(z,w); bit1 pairs (x,z),(y,w)
__device__ __forceinline__ void bf_comps(float4 &a) {
  BFLY(a.x, a.y); BFLY(a.z, a.w);
  BFLY(a.x, a.z); BFLY(a.y, a.w);
}
// reg bits: stride-1 then stride-2 over 4 regs
__device__ __forceinline__ void bf_quad(float4 v[4]) {
  bf4_pair(v[0], v[1]); bf4_pair(v[2], v[3]);
  bf4_pair(v[0], v[2]); bf4_pair(v[1], v[3]);
}

template <int CTRL>
__device__ __forceinline__ float dpp_mov(float x) {
  return __int_as_float(
      __builtin_amdgcn_mov_dpp(__float_as_int(x), CTRL, 0xF, 0xF, true));
}
// lane-bit butterfly via DPP quad_perm: 0xB1 = xor1 (lane bit0), 0x4E = xor2.
template <int CTRL>
__device__ __forceinline__ void dpp4(float4 v[4], float sgn) {
  #pragma unroll
  for (int i = 0; i < 4; ++i) {
    float px = dpp_mov<CTRL>(v[i].x);
    float py = dpp_mov<CTRL>(v[i].y);
    float pz = dpp_mov<CTRL>(v[i].z);
    float pw = dpp_mov<CTRL>(v[i].w);
    v[i].x = fmaf(sgn, v[i].x, px);
    v[i].y = fmaf(sgn, v[i].y, py);
    v[i].z = fmaf(sgn, v[i].z, pz);
    v[i].w = fmaf(sgn, v[i].w, pw);
  }
}

// Setup: pack per-(wave-half,lane) sign bits into 256 ushorts (512 B) in ws.
// mask0[h*64+lane] bit(4k+c): sign of signs[0][h<<10 | k<<8 | lane<<2 | c]
// mask1[h*64+lane] bit(4j+c): layout2 indexing (see main kernel bit maps)
__global__ void mask_setup(const int* __restrict__ signs,
                           ushort_t* __restrict__ ws) {
  const int t = threadIdx.x;            // 0..255
  const int half = (t >> 6) & 1;
  const int lane = t & 63;
  unsigned m = 0;
  if (t < 128) {
    #pragma unroll
    for (int k = 0; k < 4; ++k)
      #pragma unroll
      for (int c = 0; c < 4; ++c) {
        int e = (half << 10) | (k << 8) | (lane << 2) | c;
        m |= (unsigned)(signs[e] < 0) << (k * 4 + c);
      }
  } else {
    // layout2: e10=p0, e3=p1, e0=p2, e1=p3, e2=p4, e8=p5, e9=half
    const int e10 = lane & 1, e3 = (lane >> 1) & 1, e0 = (lane >> 2) & 1;
    const int e1 = (lane >> 3) & 1, e2 = (lane >> 4) & 1, e8 = (lane >> 5) & 1;
    const int base = e0 | (e1 << 1) | (e2 << 2) | (e3 << 3)
                   | (e8 << 8) | (half << 9) | (e10 << 10);
    #pragma unroll
    for (int j = 0; j < 4; ++j)
      #pragma unroll
      for (int c = 0; c < 4; ++c) {
        int e = base | ((c & 1) << 4) | ((c >> 1) << 5)
                     | ((j & 1) << 6) | ((j >> 1) << 7);
        m |= (unsigned)(signs[DIM + e] < 0) << (j * 4 + c);
      }
  }
  ws[t] = (ushort_t)m;
}

// Block = 256 threads = 4 waves = 2 rows; wave w: row half h = w&1.
// Each wave: 16 floats/lane (4 float4). 22 FWHT stages split 6 + 11 + 5
// across two LDS transposes; signs applied from precomputed bitmasks.
__global__ __launch_bounds__(256, 8) void srht2_kernel(
    const float* __restrict__ x, const ushort_t* __restrict__ masks,
    float* __restrict__ out) {
  __shared__ __align__(16) float lds[2][DIM];
  const int tid  = threadIdx.x;
  const int lane = tid & 63;
  const int w    = tid >> 6;
  const int h    = w & 1;
  const int rw   = w >> 1;
  const size_t row = (size_t)blockIdx.x * 2 + rw;
  float* L = lds[rw];

  const float sgnA = (lane & 1) ? -1.f : 1.f;
  const float sgnB = (lane & 2) ? -1.f : 1.f;

  const unsigned m0 = masks[(h << 6) | lane];
  const unsigned m1 = masks[128 + ((h << 6) | lane)];

  const int p0 = lane & 1,        p1 = (lane >> 1) & 1, p2 = (lane >> 2) & 1;
  const int p3 = (lane >> 3) & 1, p4 = (lane >> 4) & 1, p5 = (lane >> 5) & 1;

  // ---- load (layout1: comps=e0e1, regs k=e8e9, lane=e2..e7, h=e10) ----
  const float4* __restrict__ xr = (const float4*)(x + row * DIM);
  float4 v[4];
  #pragma unroll
  for (int k = 0; k < 4; ++k) v[k] = xr[(h << 8) + (k << 6) + lane];

  // pass-1 sign flip
  #pragma unroll
  for (int k = 0; k < 4; ++k) {
    v[k].x = flipbit(v[k].x, m0, 4 * k + 0);
    v[k].y = flipbit(v[k].y, m0, 4 * k + 1);
    v[k].z = flipbit(v[k].z, m0, 4 * k + 2);
    v[k].w = flipbit(v[k].w, m0, 4 * k + 3);
  }
  // phase1: bits e0,e1 (comps), e8,e9 (regs), e2,e3 (DPP)
  #pragma unroll
  for (int k = 0; k < 4; ++k) bf_comps(v[k]);
  bf_quad(v);
  dpp4<0xB1>(v, sgnA);
  dpp4<0x4E>(v, sgnB);

  // ---- T1 write: sigma(e) = e4 | e5<<1 | (e6^e2)<<2 | (e7^e3)<<3 |
  //                 e1<<4 | e0<<5 | e2<<6 | e3<<7 | e8<<8 | e9<<9 | e10<<10
  {
    const int Wb = p2 | (p3 << 1) | ((p4 ^ p0) << 2) | ((p5 ^ p1) << 3)
                 | (p0 << 6) | (p1 << 7) | (h << 10);
    #pragma unroll
    for (int k = 0; k < 4; ++k) {
      float* p = L + Wb + (k << 8);
      p[0]  = v[k].x;   // (e0,e1)=(0,0)
      p[16] = v[k].z;   // e1=1 -> +16
      p[32] = v[k].y;   // e0=1 -> +32
      p[48] = v[k].w;
    }
  }
  __syncthreads();
  // ---- T1 read (layout2: comps=e4e5, regs j=e6e7; lane: e10,e3,e0,e1,e2,e8; h'=e9)
  float4 u[4];
  {
    const int R = (p3 << 4) | (p2 << 5) | (p4 << 6) | (p1 << 7)
                | (p5 << 8) | (h << 9) | (p0 << 10);
    const int key = p4 | (p1 << 1);
    #pragma unroll
    for (int j = 0; j < 4; ++j)
      u[j] = *(const float4*)(L + R + ((j ^ key) << 2));
  }
  // phase2a (finish pass 1): e4,e5 (comps), e6,e7 (regs), e10 (DPP lane0)
  #pragma unroll
  for (int j = 0; j < 4; ++j) bf_comps(u[j]);
  bf_quad(u);
  dpp4<0xB1>(u, sgnA);
  // pass-2 sign flip (layout2 indexing)
  #pragma unroll
  for (int j = 0; j < 4; ++j) {
    u[j].x = flipbit(u[j].x, m1, 4 * j + 0);
    u[j].y = flipbit(u[j].y, m1, 4 * j + 1);
    u[j].z = flipbit(u[j].z, m1, 4 * j + 2);
    u[j].w = flipbit(u[j].w, m1, 4 * j + 3);
  }
  // phase2b (pass 2): e4,e5, e6,e7, e10 (DPP lane0), e3 (DPP lane1)
  #pragma unroll
  for (int j = 0; j < 4; ++j) bf_comps(u[j]);
  bf_quad(u);
  dpp4<0xB1>(u, sgnA);
  dpp4<0x4E>(u, sgnB);
  __syncthreads();
  // ---- T2 write: sigma2(e) = e0 | e1<<1 | (e8^e6)<<2 | (e9^e7)<<3 |
  //                 e4<<4 | e5<<5 | e6<<6 | e7<<7 | e2<<8 | e3<<9 | e10<<10
  {
    const int base2 = p2 | (p3 << 1) | (p4 << 8) | (p1 << 9) | (p0 << 10);
    #pragma unroll
    for (int j = 0; j < 4; ++j) {
      const int j0 = j & 1, j1 = j >> 1;
      float* p = L + (base2 | ((p5 ^ j0) << 2) | ((h ^ j1) << 3)
                            | (j0 << 6) | (j1 << 7));
      p[0]  = u[j].x;   // (e4,e5)=(0,0)
      p[16] = u[j].y;   // e4=1
      p[32] = u[j].z;   // e5=1
      p[48] = u[j].w;
    }
  }
  __syncthreads();
  // ---- T2 read (layout3: comps=e0e1, regs k=e8e9; lane: e2..e7; h''=e10)
  {
    const int R2 = (p2 << 4) | (p3 << 5) | (p4 << 6) | (p5 << 7)
                 | (p0 << 8) | (p1 << 9) | (h << 10);
    const int key2 = p4 | (p5 << 1);
    #pragma unroll
    for (int k = 0; k < 4; ++k)
      v[k] = *(const float4*)(L + R2 + ((k ^ key2) << 2));
  }
  // phase3 (finish pass 2): e0,e1 (comps), e8,e9 (regs), e2 (DPP lane0)
  #pragma unroll
  for (int k = 0; k < 4; ++k) bf_comps(v[k]);
  bf_quad(v);
  dpp4<0xB1>(v, sgnA);

  // ---- scale (exact pow2) + coalesced nontemporal store ----
  const float sc = 1.0f / 2048.0f;
  fvec4* __restrict__ orow = (fvec4*)(out + row * DIM);
  #pragma unroll
  for (int k = 0; k < 4; ++k) {
    fvec4 t;
    t.x = v[k].x * sc; t.y = v[k].y * sc;
    t.z = v[k].z * sc; t.w = v[k].w * sc;
    __builtin_nontemporal_store(t, &orow[lane + (k << 6) + (h << 8)]);
  }
}

extern "C" void kernel_launch(void* const* d_in, const int* in_sizes, int n_in,
                              void* d_out, int out_size, void* d_ws, size_t ws_size,
                              hipStream_t stream) {
  const float* x     = (const float*)d_in[0];
  const int*   signs = (const int*)d_in[1];
  float*       out   = (float*)d_out;
  ushort_t*    ws    = (ushort_t*)d_ws;   // 512 B of packed sign masks
  const int nrows   = in_sizes[0] / DIM;  // 16384
  const int nblocks = nrows / 2;          // 2 rows per 256-thread block

  hipLaunchKernelGGL(mask_setup, dim3(1), dim3(256), 0, stream, signs, ws);
  hipLaunchKernelGGL(srht2_kernel, dim3(nblocks), dim3(256), 0, stream,
                     x, ws, out);
}